// Round 9
// baseline (378.481 us; speedup 1.0000x reference)
//
#include <hip/hip_runtime.h>
#include <hip/hip_bf16.h>

// Problem constants (from reference)
#define BB 4096
#define VV 200
#define FF 4
#define GG 80
#define RR 16
#define NLIG 7
#define PVQ 248     // 200 vertices + <=16*3 pad slots (quad-aligned classes)
// f32(2*pi) = 0x40C90FDB; ANG_STEP = f32(2*pi)/16 exactly
#define TWO_PI_F 6.2831853071795864769f
#define ANG_STEP 0.39269908169872414f
#define INV_ANG_STEP 2.5464790894703255f
#define LOG2E_F 1.4426950408889634f
#define EXPCUT 26.0f    // skip when contribution < 2^-26 (err <<< threshold)

typedef float v2f __attribute__((ext_vector_type(2)));

__device__ __forceinline__ float fexp2(float x) {
#if __has_builtin(__builtin_amdgcn_exp2f)
    return __builtin_amdgcn_exp2f(x);   // raw v_exp_f32
#else
    return exp2f(x);
#endif
}

// packed f32 ops (VOP3P): one instruction, 2 f32 lanes (double-pumped, 4cy)
__device__ __forceinline__ v2f pk_fma(v2f a, v2f b, v2f c) {
    v2f d;
    asm("v_pk_fma_f32 %0, %1, %2, %3" : "=v"(d) : "v"(a), "v"(b), "v"(c));
    return d;
}
__device__ __forceinline__ v2f pk_mul(v2f a, v2f b) {
    v2f d;
    asm("v_pk_mul_f32 %0, %1, %2" : "=v"(d) : "v"(a), "v"(b));
    return d;
}
__device__ __forceinline__ v2f pk_add(v2f a, v2f b) {
    v2f d;
    asm("v_pk_add_f32 %0, %1, %2" : "=v"(d) : "v"(a), "v"(b));
    return d;
}
__device__ __forceinline__ v2f bc2(float x) { v2f r; r.x = x; r.y = x; return r; }

// j-space chain for one vertex of class C (j0 == C):
//   T[j] = M * B^j * K[j], j = 0..15 ; contribution lands at r = (j - C) & 15.
// Even/odd j sub-chains (ratio B^2) packed into v2f; accumulate into
// aggE (even classes) or aggO (odd classes). All indices compile-time.
template<int C>
__device__ __forceinline__ void chain(const v2f (&Kp)[8], v2f (&aggE)[8],
                                      v2f (&aggO)[8], float M, float B) {
    const float B2 = B * B;
    v2f u;  u.x = M;  u.y = M * B;
    v2f w2; w2.x = B2; w2.y = B2;
    #pragma unroll
    for (int i = 0; i < 8; ++i) {
        const int idx = ((2 * i + 16 - C) & 15) >> 1;   // constant after unroll
        if constexpr ((C & 1) == 0) aggE[idx] = pk_fma(u, Kp[i], aggE[idx]);
        else                        aggO[idx] = pk_fma(u, Kp[i], aggO[idx]);
        if (i < 7) u = pk_mul(u, w2);
    }
}

// LDS union layout (phase 1 / phase 2 separated by a barrier). SoA pv arrays,
// all quad(16B)-aligned so class segments (multiples of 4) load as b128.
#define OFF_RHO   0                      // float[248]  992
#define OFF_A0    992                    // float[248]  992
#define OFF_VA    1984                   // float[248]  992
#define OFF_BV    2976                   // float[248]  992
#define OFF_PV_X  3968                   // float[4][248] 3968
#define OFF_CNTW  7936                   // int[5][16]  320
#define OFF_PS    8256                   // int[17]     68
#define OFF_SSIG  8324                   // float[2]    8
#define OFF_AGGL  0                      // float[4][16][80] 20480 (phase 2)
#define OFF_DESC  20480                  // float[320]  1280
#define OFF_HP    21760                  // float[4][80] 1280
#define UNI_SIZE  23040

// ---------------------------------------------------------------------------
// Kernel A: per-sample b. Masked vertices dropped (exact +-0). Kept vertices
// bucket-sorted by j0 via wave-ballot counting sort; classes padded to
// multiples of 4 (pads all-zero -> exact no-op). Chain phase uses BAND lane
// mapping (wave = rho band) so the rho cull is wave-uniform. Class loops
// process QUADS: 1 b128 rho load -> cull -> 4 b128 loads + pk setup for two
// pairs -> up to 4 guarded chains. GEMV/fc1 keep the flat (f,g) mapping.
// One block per b, 320 threads.
// ---------------------------------------------------------------------------
__global__ __launch_bounds__(320, 6) void masif_main(
    const float* __restrict__ xin,      // [B,V,F]
    const float* __restrict__ rho,      // [B,V]
    const float* __restrict__ theta,    // [B,V]
    const float* __restrict__ mask,     // [B,V]
    const float* __restrict__ mu_rho,   // [F,G]
    const float* __restrict__ mu_theta, // [F,G]
    const float* __restrict__ sigma_rho,   // [F,G]
    const float* __restrict__ sigma_theta, // [F,G]
    const float* __restrict__ conv_W,   // [F,G,G]
    const float* __restrict__ conv_b,   // [F,G]
    const float* __restrict__ fc1_W,    // [G, F*G]
    const float* __restrict__ fc1_b,    // [G]
    float* __restrict__ xbuf)           // [B,G] out
{
    const int b = blockIdx.x;
    const int t = threadIdx.x;
    const int lane = t & 63;
    const int w = t >> 6;            // wave 0..4 == rho band
    const int fb = lane >> 4;        // chain-phase f   0..3
    const int gb = w * 16 + (lane & 15); // chain-phase g 0..79
    const int f = t / GG;            // GEMV/fc1-phase f
    const int g = t % GG;            // GEMV/fc1-phase g

    __shared__ __align__(16) char U[UNI_SIZE];
    float* pv_rho = reinterpret_cast<float*>(U + OFF_RHO);
    float* pv_a0  = reinterpret_cast<float*>(U + OFF_A0);
    float* pv_va  = reinterpret_cast<float*>(U + OFF_VA);
    float* pv_bv  = reinterpret_cast<float*>(U + OFF_BV);
    float (*pv_x)[PVQ] = reinterpret_cast<float(*)[PVQ]>(U + OFF_PV_X);
    int (*cntw)[RR] = reinterpret_cast<int(*)[RR]>(U + OFF_CNTW);
    int* ps = reinterpret_cast<int*>(U + OFF_PS);
    float* ssig = reinterpret_cast<float*>(U + OFF_SSIG);
    float (*aggL)[RR][GG] = reinterpret_cast<float(*)[RR][GG]>(U + OFF_AGGL);
    float* desc_s = reinterpret_cast<float*>(U + OFF_DESC);
    float* hp_s = reinterpret_cast<float*>(U + OFF_HP);

    // chain-phase per-(fb,gb) parameters (band mapping)
    const int pidx = fb * GG + gb;
    const float mr  = mu_rho[pidx];
    const float mt  = mu_theta[pidx];
    const float sr  = sigma_rho[pidx];
    const float st  = sigma_theta[pidx];
    const float nisr2 = -LOG2E_F / (sr * sr + 1e-5f);
    const float nist2 = -LOG2E_F / (st * st + 1e-5f);
    const float c1 = 2.0f * ANG_STEP * nist2;       // B(x) = 2^(c1*x)

    // ---- phase 0: classify (masked vertices dropped: exact zeros) ----
    float rh = 0.f, a0 = 0.f, mx0 = 0.f, mx1 = 0.f, mx2 = 0.f, mx3 = 0.f;
    int j0 = 0;
    bool keep = false;
    if (t < VV) {
        const int idx = b * VV + t;
        const float th = theta[idx];
        const float m  = mask[idx];
        keep = (m != 0.0f);
        rh = rho[idx];
        j0 = (int)(th * INV_ANG_STEP);
        if (j0 > RR - 1) j0 = RR - 1;               // guard th ~ 2*pi rounding
        a0 = fmaf(-(float)j0, ANG_STEP, th);        // th - j0*step
        const float4 xv = *reinterpret_cast<const float4*>(&xin[idx * 4]);
        mx0 = m * xv.x; mx1 = m * xv.y; mx2 = m * xv.z; mx3 = m * xv.w;
    }
    if (t == 0) { ssig[0] = nisr2; ssig[1] = nist2; }

    // packed K table K[m] = 2^(nist2*Dlt^2*m^2) (per-thread regs)
    v2f Kp[8];
    #pragma unroll
    for (int i = 0; i < 8; ++i) {
        const float m0 = (float)(2 * i), m1 = (float)(2 * i + 1);
        Kp[i].x = fexp2(nist2 * (ANG_STEP * ANG_STEP) * m0 * m0);
        Kp[i].y = fexp2(nist2 * (ANG_STEP * ANG_STEP) * m1 * m1);
    }

    // ---- ballot counting sort: rank-in-wave + per-wave class counts ----
    int rank = 0, cnt_lane = 0;
    #pragma unroll
    for (int c = 0; c < RR; ++c) {
        const unsigned long long mbl = __ballot(keep && (j0 == c));
        if (keep && (j0 == c))
            rank = (int)__popcll(mbl & ((1ull << lane) - 1ull));
        if (lane == c) cnt_lane = (int)__popcll(mbl);
    }
    if (lane < RR) cntw[w][lane] = cnt_lane;
    __syncthreads();   // B1: cntw + ssig ready

    // sigma-uniformity flag (fast path validity); vertex precompute
    const float s_nisr2 = ssig[0], s_nist2 = ssig[1];
    const int myflag = (__float_as_int(nisr2) == __float_as_int(s_nisr2)) &&
                       (__float_as_int(nist2) == __float_as_int(s_nist2));
    float va = 0.f, Bv = 0.f;
    if (t < VV) {
        const float s_c1 = 2.0f * ANG_STEP * s_nist2;
        va = fmaf(a0 * a0, s_nist2, (rh * rh) * s_nisr2);
        Bv = fexp2(s_c1 * a0);
    }
    // t0: quad-padded prefix; all: zero-fill pv (pads -> exact no-ops)
    if (t == 0) {
        int s = 0;
        #pragma unroll
        for (int c = 0; c < RR; ++c) {
            ps[c] = s;
            const int cc = cntw[0][c] + cntw[1][c] + cntw[2][c]
                         + cntw[3][c] + cntw[4][c];
            s += (cc + 3) & ~3;
        }
        ps[RR] = s;
    }
    if (t < PVQ) {
        pv_rho[t] = 0.f; pv_a0[t] = 0.f; pv_va[t] = 0.f; pv_bv[t] = 0.f;
        pv_x[0][t] = 0.f; pv_x[1][t] = 0.f; pv_x[2][t] = 0.f; pv_x[3][t] = 0.f;
    }
    const int uniOK = __syncthreads_and(myflag);   // B2: ps + zero-fill ready

    // scatter kept vertices (stable within class -> deterministic)
    if (keep) {
        int off = 0;
        #pragma unroll
        for (int w2 = 0; w2 < 4; ++w2)
            if (w2 < w) off += cntw[w2][j0];
        const int pos = ps[j0] + off + rank;
        pv_rho[pos] = rh; pv_a0[pos] = a0; pv_va[pos] = va; pv_bv[pos] = Bv;
        pv_x[0][pos] = mx0; pv_x[1][pos] = mx1;
        pv_x[2][pos] = mx2; pv_x[3][pos] = mx3;
    }
    __syncthreads();   // B3: pv ready

    // ---- gaussian aggregation: 16 class loops, quad bodies, pk chains ----
    v2f aggE[8], aggO[8];
    #pragma unroll
    for (int i = 0; i < 8; ++i) {
        aggE[i].x = 0.f; aggE[i].y = 0.f;
        aggO[i].x = 0.f; aggO[i].y = 0.f;
    }

    if (uniOK) {
        // fast path: exponent = va + Cc + ct1*a0 + ct2*rho ; B = Bv*Bt
        const float ct1 = -2.0f * nist2 * mt;
        const float ct2 = -2.0f * nisr2 * mr;
        const float Cc  = fmaf(mt * mt, nist2, (mr * mr) * nisr2);
        const float Bt  = fexp2(-c1 * mt);
        const v2f ct1_2 = bc2(ct1), ct2_2 = bc2(ct2), Cc2 = bc2(Cc), Bt2 = bc2(Bt);
        const float R2cut = EXPCUT / (-s_nisr2);   // uniform (sigma uniform)
        int sprev = 0;
#define CLSF(C) { \
        const int send = __builtin_amdgcn_readfirstlane(ps[(C) + 1]); \
        for (int v = sprev; v < send; v += 4) { \
            const float4 r4 = *reinterpret_cast<const float4*>(&pv_rho[v]); \
            const float dA = r4.x - mr, dB = r4.y - mr; \
            const float dC = r4.z - mr, dD = r4.w - mr; \
            const int okA = __any(dA * dA <= R2cut); \
            const int okB = __any(dB * dB <= R2cut); \
            const int okC = __any(dC * dC <= R2cut); \
            const int okD = __any(dD * dD <= R2cut); \
            if (okA | okB | okC | okD) { \
                const float4 q4 = *reinterpret_cast<const float4*>(&pv_a0[v]); \
                const float4 w4 = *reinterpret_cast<const float4*>(&pv_va[v]); \
                const float4 b4 = *reinterpret_cast<const float4*>(&pv_bv[v]); \
                const float4 s4 = *reinterpret_cast<const float4*>(&pv_x[fb][v]); \
                v2f rAB, rCD, aAB, aCD, vAB, vCD, bAB, bCD; \
                rAB.x = r4.x; rAB.y = r4.y; rCD.x = r4.z; rCD.y = r4.w; \
                aAB.x = q4.x; aAB.y = q4.y; aCD.x = q4.z; aCD.y = q4.w; \
                vAB.x = w4.x; vAB.y = w4.y; vCD.x = w4.z; vCD.y = w4.w; \
                bAB.x = b4.x; bAB.y = b4.y; bCD.x = b4.z; bCD.y = b4.w; \
                const v2f t1 = pk_fma(aAB, ct1_2, pk_fma(rAB, ct2_2, pk_add(vAB, Cc2))); \
                const v2f t2 = pk_fma(aCD, ct1_2, pk_fma(rCD, ct2_2, pk_add(vCD, Cc2))); \
                const v2f Bab = pk_mul(bAB, Bt2); \
                const v2f Bcd = pk_mul(bCD, Bt2); \
                if (okA) chain<(C)>(Kp, aggE, aggO, fexp2(t1.x) * s4.x, Bab.x); \
                if (okB) chain<(C)>(Kp, aggE, aggO, fexp2(t1.y) * s4.y, Bab.y); \
                if (okC) chain<(C)>(Kp, aggE, aggO, fexp2(t2.x) * s4.z, Bcd.x); \
                if (okD) chain<(C)>(Kp, aggE, aggO, fexp2(t2.y) * s4.w, Bcd.y); \
            } \
        } \
        sprev = send; }
        CLSF(0)  CLSF(1)  CLSF(2)  CLSF(3)
        CLSF(4)  CLSF(5)  CLSF(6)  CLSF(7)
        CLSF(8)  CLSF(9)  CLSF(10) CLSF(11)
        CLSF(12) CLSF(13) CLSF(14) CLSF(15)
#undef CLSF
    } else {
        // exact fallback: per-thread sigma, 2 exp2/vertex, no cull
        int sprev = 0;
#define CLSS(C) { \
        const int send = __builtin_amdgcn_readfirstlane(ps[(C) + 1]); \
        for (int v = sprev; v < send; v += 4) { \
            const float4 r4 = *reinterpret_cast<const float4*>(&pv_rho[v]); \
            const float4 q4 = *reinterpret_cast<const float4*>(&pv_a0[v]); \
            const float4 s4 = *reinterpret_cast<const float4*>(&pv_x[fb][v]); \
            const float rr_[4] = {r4.x, r4.y, r4.z, r4.w}; \
            const float qq_[4] = {q4.x, q4.y, q4.z, q4.w}; \
            const float ss_[4] = {s4.x, s4.y, s4.z, s4.w}; \
            _Pragma("unroll") \
            for (int u_ = 0; u_ < 4; ++u_) { \
                const float dr = rr_[u_] - mr, x = qq_[u_] - mt; \
                const float ar = (dr * dr) * nisr2; \
                const float M = fexp2(fmaf(x * x, nist2, ar)) * ss_[u_]; \
                const float Bx = fexp2(x * c1); \
                chain<(C)>(Kp, aggE, aggO, M, Bx); \
            } \
        } \
        sprev = send; }
        CLSS(0)  CLSS(1)  CLSS(2)  CLSS(3)
        CLSS(4)  CLSS(5)  CLSS(6)  CLSS(7)
        CLSS(8)  CLSS(9)  CLSS(10) CLSS(11)
        CLSS(12) CLSS(13) CLSS(14) CLSS(15)
#undef CLSS
    }
    __syncthreads();   // B3.5: all pv/ps reads done -> aggL may overlay

    // combine dual accumulators -> r-space, write to LDS (band mapping!)
    #pragma unroll
    for (int k = 0; k < 8; ++k) {
        aggL[fb][2 * k][gb]     = aggE[k].x + aggO[(k + 7) & 7].y;
        aggL[fb][2 * k + 1][gb] = aggE[k].y + aggO[k].x;
    }
    __syncthreads();   // B4: aggL ready

    // ---- conv GEMV (pk) + relu + max over rotations (flat mapping) ----
    v2f racc2[RR];
    {
        const float cb = conv_b[f * GG + g];
        #pragma unroll
        for (int r = 0; r < RR; ++r) { racc2[r].x = cb; racc2[r].y = 0.f; }
    }
    for (int g4 = 0; g4 < GG; g4 += 4) {
        const float* wp = &conv_W[(f * GG + g4) * GG + g];
        v2f wA, wB;
        wA.x = wp[0];      wA.y = wp[GG];
        wB.x = wp[2 * GG]; wB.y = wp[3 * GG];
        #pragma unroll
        for (int r = 0; r < RR; ++r) {
            const float4 a4 = *reinterpret_cast<const float4*>(&aggL[f][r][g4]);
            v2f aA, aB;
            aA.x = a4.x; aA.y = a4.y;
            aB.x = a4.z; aB.y = a4.w;
            racc2[r] = pk_fma(aA, wA, racc2[r]);
            racc2[r] = pk_fma(aB, wB, racc2[r]);
        }
    }
    float mxr = racc2[0].x + racc2[0].y;
    #pragma unroll
    for (int r = 1; r < RR; ++r) mxr = fmaxf(mxr, racc2[r].x + racc2[r].y);
    desc_s[f * GG + g] = fmaxf(mxr, 0.0f);   // disjoint from aggL region

    __syncthreads();   // B5: desc ready

    // ---- fc1 + relu (pk, 4-way k-split over f) ----
    {
        const v2f* wrow = reinterpret_cast<const v2f*>(&fc1_W[g * (FF * GG) + f * GG]);
        const v2f* drow = reinterpret_cast<const v2f*>(&desc_s[f * GG]);
        v2f a2; a2.x = 0.f; a2.y = 0.f;
        #pragma unroll 4
        for (int k = 0; k < GG / 2; ++k) a2 = pk_fma(drow[k], wrow[k], a2);
        hp_s[f * GG + g] = a2.x + a2.y;
    }
    __syncthreads();   // B6: hp ready
    if (t < GG) {
        const float a1 = ((hp_s[t] + hp_s[GG + t]) + (hp_s[2 * GG + t] + hp_s[3 * GG + t]))
                         + fc1_b[t];
        xbuf[b * GG + t] = fmaxf(a1, 0.0f);
    }
}

// ---------------------------------------------------------------------------
// Kernel B: partial gram. 64 blocks x 64 samples; deterministic.
// ---------------------------------------------------------------------------
__global__ __launch_bounds__(256) void gram_partial(
    const float* __restrict__ xbuf,   // [B,G]
    float* __restrict__ gpart)        // [64, G*G]
{
    const int blk = blockIdx.x;
    const int t = threadIdx.x;
    __shared__ float xs[64][GG];

    for (int i = t; i < 64 * GG; i += 256) {
        int bb = i / GG, jj = i % GG;
        xs[bb][jj] = xbuf[(blk * 64 + bb) * GG + jj];
    }
    __syncthreads();

    const int ti = t / 16, tj = t % 16;
    float acc[5][5];
    #pragma unroll
    for (int u = 0; u < 5; ++u)
        #pragma unroll
        for (int w = 0; w < 5; ++w) acc[u][w] = 0.0f;

    for (int bb = 0; bb < 64; ++bb) {
        float xi[5], xj[5];
        #pragma unroll
        for (int u = 0; u < 5; ++u) { xi[u] = xs[bb][ti * 5 + u]; xj[u] = xs[bb][tj * 5 + u]; }
        #pragma unroll
        for (int u = 0; u < 5; ++u)
            #pragma unroll
            for (int w = 0; w < 5; ++w)
                acc[u][w] = fmaf(xi[u], xj[w], acc[u][w]);
    }

    #pragma unroll
    for (int u = 0; u < 5; ++u)
        #pragma unroll
        for (int w = 0; w < 5; ++w)
            gpart[blk * (GG * GG) + (ti * 5 + u) * GG + (tj * 5 + w)] = acc[u][w];
}

// ---------------------------------------------------------------------------
// Kernel C1: 64 blocks; block p owns k-range [p*100, p*100+100): reduce gram
// partials (ordered, deterministic) and compute partial fc2 dot products.
// ---------------------------------------------------------------------------
__global__ __launch_bounds__(128) void head_partial(
    const float* __restrict__ gpart,  // [64, G*G]
    const float* __restrict__ fc2_W,  // [64, G*G]
    float* __restrict__ hpp)          // [64, 64]
{
    const int p = blockIdx.x;   // 0..63
    const int t = threadIdx.x;
    __shared__ float gs[100];

    if (t < 100) {
        const int k = p * 100 + t;
        float s = 0.f;
        #pragma unroll 8
        for (int q = 0; q < 64; ++q) s += gpart[q * (GG * GG) + k];
        gs[t] = s * (1.0f / 4096.0f);
    }
    __syncthreads();
    if (t < 64) {
        const float* w = &fc2_W[t * (GG * GG) + p * 100];
        float a = 0.f;
        #pragma unroll 4
        for (int k = 0; k < 100; ++k) a = fmaf(gs[k], w[k], a);
        hpp[p * 64 + t] = a;
    }
}

// ---------------------------------------------------------------------------
// Kernel C2: reduce hpp (ordered), fc2 bias+relu, fco head.
// ---------------------------------------------------------------------------
__global__ __launch_bounds__(256) void head_final(
    const float* __restrict__ hpp,    // [64, 64]
    const float* __restrict__ fc2_b,  // [64]
    const float* __restrict__ fco_W,  // [NLIG, 64]
    const float* __restrict__ fco_b,  // [NLIG]
    float* __restrict__ out)          // [NLIG]
{
    const int t = threadIdx.x;
    const int part = t >> 6, j = t & 63;
    __shared__ float hq[4][64];
    __shared__ float hs[64];
    float a = 0.f;
    #pragma unroll 4
    for (int p = part * 16; p < part * 16 + 16; ++p) a += hpp[p * 64 + j];
    hq[part][j] = a;
    __syncthreads();
    if (t < 64)
        hs[t] = fmaxf(((hq[0][t] + hq[1][t]) + (hq[2][t] + hq[3][t])) + fc2_b[t], 0.0f);
    __syncthreads();
    if (t < NLIG) {
        float o = fco_b[t];
        #pragma unroll
        for (int jj = 0; jj < 64; ++jj) o = fmaf(hs[jj], fco_W[t * 64 + jj], o);
        out[t] = o;
    }
}

// ---------------------------------------------------------------------------
extern "C" void kernel_launch(void* const* d_in, const int* in_sizes, int n_in,
                              void* d_out, int out_size, void* d_ws, size_t ws_size,
                              hipStream_t stream) {
    const float* input_feat  = (const float*)d_in[0];
    const float* rho         = (const float*)d_in[1];
    const float* theta       = (const float*)d_in[2];
    const float* mask        = (const float*)d_in[3];
    const float* mu_rho      = (const float*)d_in[4];
    const float* mu_theta    = (const float*)d_in[5];
    const float* sigma_rho   = (const float*)d_in[6];
    const float* sigma_theta = (const float*)d_in[7];
    const float* conv_W      = (const float*)d_in[8];
    const float* conv_b      = (const float*)d_in[9];
    const float* fc1_W       = (const float*)d_in[10];
    const float* fc1_b       = (const float*)d_in[11];
    const float* fc2_W       = (const float*)d_in[12];
    const float* fc2_b       = (const float*)d_in[13];
    const float* fco_W       = (const float*)d_in[14];
    const float* fco_b       = (const float*)d_in[15];

    float* xbuf  = (float*)d_ws;                                      // [B,G]
    float* gpart = (float*)((char*)d_ws + (size_t)BB * GG * 4);       // [64,6400]
    float* hpp   = (float*)((char*)d_ws + (size_t)BB * GG * 4
                                        + (size_t)64 * GG * GG * 4);  // [64,64]

    masif_main<<<BB, 320, 0, stream>>>(input_feat, rho, theta, mask,
                                       mu_rho, mu_theta, sigma_rho, sigma_theta,
                                       conv_W, conv_b, fc1_W, fc1_b, xbuf);
    gram_partial<<<64, 256, 0, stream>>>(xbuf, gpart);
    head_partial<<<64, 128, 0, stream>>>(gpart, fc2_W, hpp);
    head_final<<<1, 256, 0, stream>>>(hpp, fc2_b, fco_W, fco_b, (float*)d_out);
}

// Round 10
// 286.690 us; speedup vs baseline: 1.3202x; 1.3202x over previous
//
#include <hip/hip_runtime.h>
#include <hip/hip_bf16.h>

// Problem constants (from reference)
#define BB 4096
#define VV 200
#define FF 4
#define GG 80
#define RR 16
#define NLIG 7
#define PVMAX 216   // 200 vertices + <=16 pad slots (even-aligned classes)
// f32(2*pi) = 0x40C90FDB; ANG_STEP = f32(2*pi)/16 exactly
#define TWO_PI_F 6.2831853071795864769f
#define ANG_STEP 0.39269908169872414f
#define INV_ANG_STEP 2.5464790894703255f
#define LOG2E_F 1.4426950408889634f
#define EXPCUT 26.0f    // skip when contribution < 2^-26 (err <<< threshold)

typedef float v2f __attribute__((ext_vector_type(2)));

__device__ __forceinline__ float fexp2(float x) {
#if __has_builtin(__builtin_amdgcn_exp2f)
    return __builtin_amdgcn_exp2f(x);   // raw v_exp_f32
#else
    return exp2f(x);
#endif
}

// packed f32 ops (VOP3P): one instruction, 2 f32 lanes (double-pumped, 4cy)
__device__ __forceinline__ v2f pk_fma(v2f a, v2f b, v2f c) {
    v2f d;
    asm("v_pk_fma_f32 %0, %1, %2, %3" : "=v"(d) : "v"(a), "v"(b), "v"(c));
    return d;
}
__device__ __forceinline__ v2f pk_mul(v2f a, v2f b) {
    v2f d;
    asm("v_pk_mul_f32 %0, %1, %2" : "=v"(d) : "v"(a), "v"(b));
    return d;
}
__device__ __forceinline__ v2f pk_add(v2f a, v2f b) {
    v2f d;
    asm("v_pk_add_f32 %0, %1, %2" : "=v"(d) : "v"(a), "v"(b));
    return d;
}
__device__ __forceinline__ v2f bc2(float x) { v2f r; r.x = x; r.y = x; return r; }

// j-space chain for one vertex of class C (j0 == C):
//   T[j] = M * B^j * K[j], j = 0..15 ; contribution lands at r = (j - C) & 15.
// Even/odd j sub-chains (ratio B^2) packed into v2f; accumulate into
// aggE (even classes) or aggO (odd classes). All indices compile-time.
template<int C>
__device__ __forceinline__ void chain(const v2f (&Kp)[8], v2f (&aggE)[8],
                                      v2f (&aggO)[8], float M, float B) {
    const float B2 = B * B;
    v2f u;  u.x = M;  u.y = M * B;
    v2f w2; w2.x = B2; w2.y = B2;
    #pragma unroll
    for (int i = 0; i < 8; ++i) {
        const int idx = ((2 * i + 16 - C) & 15) >> 1;   // constant after unroll
        if constexpr ((C & 1) == 0) aggE[idx] = pk_fma(u, Kp[i], aggE[idx]);
        else                        aggO[idx] = pk_fma(u, Kp[i], aggO[idx]);
        if (i < 7) u = pk_mul(u, w2);
    }
}

// LDS union layout (phase 1 / phase 2 separated by a barrier). SoA pv arrays.
#define OFF_RHO   0                      // float[216]  864
#define OFF_A0    864                    // float[216]  864
#define OFF_VA    1728                   // float[216]  864
#define OFF_BV    2592                   // float[216]  864
#define OFF_PV_X  3456                   // float[4][216] 3456
#define OFF_CNTW  6912                   // int[5][16]  320
#define OFF_PS    7232                   // int[17]     68
#define OFF_SSIG  7300                   // float[2]    8
#define OFF_AGGL  0                      // float[4][16][80] 20480 (phase 2)
#define OFF_DESC  20480                  // float[320]  1280
#define OFF_HP    21760                  // float[4][80] 1280
#define UNI_SIZE  23104

// ---------------------------------------------------------------------------
// Kernel A: per-sample b. Masked vertices dropped (exact +-0). Kept vertices
// bucket-sorted by j0 via wave-ballot counting sort; classes padded even
// (pads s=0 -> exact no-op). Chain phase uses BAND lane mapping: wave w owns
// rho-band w (g = w*16 + thetac, lane = f*16 + thetac), so the rho-Gaussian
// cull (skip vertex when exponent < -26 for ALL lanes, via __any: exact,
// data-independent) is wave-uniform -> branch-free divergence. ~27% of
// chains skipped on this data. GEMV/fc1 phases keep the flat (f,g) mapping.
// One block per b, 320 threads.
// NOTE (round 9 lesson): pair-wide bodies only. Quad-wide bodies exceed the
// ~64-VGPR budget of the 6-block/CU occupancy -> scratch spills (WRITE_SIZE
// 1.3 MB -> 33 MB, dur +31%). Do not widen without checking resource usage.
// ---------------------------------------------------------------------------
__global__ __launch_bounds__(320, 6) void masif_main(
    const float* __restrict__ xin,      // [B,V,F]
    const float* __restrict__ rho,      // [B,V]
    const float* __restrict__ theta,    // [B,V]
    const float* __restrict__ mask,     // [B,V]
    const float* __restrict__ mu_rho,   // [F,G]
    const float* __restrict__ mu_theta, // [F,G]
    const float* __restrict__ sigma_rho,   // [F,G]
    const float* __restrict__ sigma_theta, // [F,G]
    const float* __restrict__ conv_W,   // [F,G,G]
    const float* __restrict__ conv_b,   // [F,G]
    const float* __restrict__ fc1_W,    // [G, F*G]
    const float* __restrict__ fc1_b,    // [G]
    float* __restrict__ xbuf)           // [B,G] out
{
    const int b = blockIdx.x;
    const int t = threadIdx.x;
    const int lane = t & 63;
    const int w = t >> 6;            // wave 0..4 == rho band
    const int fb = lane >> 4;        // chain-phase f   0..3
    const int gb = w * 16 + (lane & 15); // chain-phase g 0..79
    const int f = t / GG;            // GEMV/fc1-phase f
    const int g = t % GG;            // GEMV/fc1-phase g

    __shared__ __align__(16) char U[UNI_SIZE];
    float* pv_rho = reinterpret_cast<float*>(U + OFF_RHO);
    float* pv_a0  = reinterpret_cast<float*>(U + OFF_A0);
    float* pv_va  = reinterpret_cast<float*>(U + OFF_VA);
    float* pv_bv  = reinterpret_cast<float*>(U + OFF_BV);
    float (*pv_x)[PVMAX] = reinterpret_cast<float(*)[PVMAX]>(U + OFF_PV_X);
    int (*cntw)[RR] = reinterpret_cast<int(*)[RR]>(U + OFF_CNTW);
    int* ps = reinterpret_cast<int*>(U + OFF_PS);
    float* ssig = reinterpret_cast<float*>(U + OFF_SSIG);
    float (*aggL)[RR][GG] = reinterpret_cast<float(*)[RR][GG]>(U + OFF_AGGL);
    float* desc_s = reinterpret_cast<float*>(U + OFF_DESC);
    float* hp_s = reinterpret_cast<float*>(U + OFF_HP);

    // chain-phase per-(fb,gb) parameters (band mapping)
    const int pidx = fb * GG + gb;
    const float mr  = mu_rho[pidx];
    const float mt  = mu_theta[pidx];
    const float sr  = sigma_rho[pidx];
    const float st  = sigma_theta[pidx];
    const float nisr2 = -LOG2E_F / (sr * sr + 1e-5f);
    const float nist2 = -LOG2E_F / (st * st + 1e-5f);
    const float c1 = 2.0f * ANG_STEP * nist2;       // B(x) = 2^(c1*x)

    // ---- phase 0: classify (masked vertices dropped: exact zeros) ----
    float rh = 0.f, a0 = 0.f, mx0 = 0.f, mx1 = 0.f, mx2 = 0.f, mx3 = 0.f;
    int j0 = 0;
    bool keep = false;
    if (t < VV) {
        const int idx = b * VV + t;
        const float th = theta[idx];
        const float m  = mask[idx];
        keep = (m != 0.0f);
        rh = rho[idx];
        j0 = (int)(th * INV_ANG_STEP);
        if (j0 > RR - 1) j0 = RR - 1;               // guard th ~ 2*pi rounding
        a0 = fmaf(-(float)j0, ANG_STEP, th);        // th - j0*step
        const float4 xv = *reinterpret_cast<const float4*>(&xin[idx * 4]);
        mx0 = m * xv.x; mx1 = m * xv.y; mx2 = m * xv.z; mx3 = m * xv.w;
    }
    if (t == 0) { ssig[0] = nisr2; ssig[1] = nist2; }

    // packed K table K[m] = 2^(nist2*Dlt^2*m^2) (per-thread regs)
    v2f Kp[8];
    #pragma unroll
    for (int i = 0; i < 8; ++i) {
        const float m0 = (float)(2 * i), m1 = (float)(2 * i + 1);
        Kp[i].x = fexp2(nist2 * (ANG_STEP * ANG_STEP) * m0 * m0);
        Kp[i].y = fexp2(nist2 * (ANG_STEP * ANG_STEP) * m1 * m1);
    }

    // ---- ballot counting sort: rank-in-wave + per-wave class counts ----
    int rank = 0, cnt_lane = 0;
    #pragma unroll
    for (int c = 0; c < RR; ++c) {
        const unsigned long long mbl = __ballot(keep && (j0 == c));
        if (keep && (j0 == c))
            rank = (int)__popcll(mbl & ((1ull << lane) - 1ull));
        if (lane == c) cnt_lane = (int)__popcll(mbl);
    }
    if (lane < RR) cntw[w][lane] = cnt_lane;
    __syncthreads();   // B1: cntw + ssig ready

    // sigma-uniformity flag (fast path validity); vertex precompute
    const float s_nisr2 = ssig[0], s_nist2 = ssig[1];
    const int myflag = (__float_as_int(nisr2) == __float_as_int(s_nisr2)) &&
                       (__float_as_int(nist2) == __float_as_int(s_nist2));
    float va = 0.f, Bv = 0.f;
    if (t < VV) {
        const float s_c1 = 2.0f * ANG_STEP * s_nist2;
        va = fmaf(a0 * a0, s_nist2, (rh * rh) * s_nisr2);
        Bv = fexp2(s_c1 * a0);
    }
    // t0: padded prefix; all: zero-fill pv (pads -> exact no-ops)
    if (t == 0) {
        int s = 0;
        #pragma unroll
        for (int c = 0; c < RR; ++c) {
            ps[c] = s;
            const int cc = cntw[0][c] + cntw[1][c] + cntw[2][c]
                         + cntw[3][c] + cntw[4][c];
            s += (cc + 1) & ~1;
        }
        ps[RR] = s;
    }
    if (t < PVMAX) {
        pv_rho[t] = 0.f; pv_a0[t] = 0.f; pv_va[t] = 0.f; pv_bv[t] = 0.f;
        pv_x[0][t] = 0.f; pv_x[1][t] = 0.f; pv_x[2][t] = 0.f; pv_x[3][t] = 0.f;
    }
    const int uniOK = __syncthreads_and(myflag);   // B2: ps + zero-fill ready

    // scatter kept vertices (stable within class -> deterministic)
    if (keep) {
        int off = 0;
        #pragma unroll
        for (int w2 = 0; w2 < 4; ++w2)
            if (w2 < w) off += cntw[w2][j0];
        const int pos = ps[j0] + off + rank;
        pv_rho[pos] = rh; pv_a0[pos] = a0; pv_va[pos] = va; pv_bv[pos] = Bv;
        pv_x[0][pos] = mx0; pv_x[1][pos] = mx1;
        pv_x[2][pos] = mx2; pv_x[3][pos] = mx3;
    }
    __syncthreads();   // B3: pv ready

    // ---- gaussian aggregation: 16 class loops, pair-unrolled, pk chains ----
    v2f aggE[8], aggO[8];
    #pragma unroll
    for (int i = 0; i < 8; ++i) {
        aggE[i].x = 0.f; aggE[i].y = 0.f;
        aggO[i].x = 0.f; aggO[i].y = 0.f;
    }

    if (uniOK) {
        // fast path: exponent = va + Cc + ct1*a0 + ct2*rho ; B = Bv*Bt
        const float ct1 = -2.0f * nist2 * mt;
        const float ct2 = -2.0f * nisr2 * mr;
        const float Cc  = fmaf(mt * mt, nist2, (mr * mr) * nisr2);
        const float Bt  = fexp2(-c1 * mt);
        const v2f ct1_2 = bc2(ct1), ct2_2 = bc2(ct2), Cc2 = bc2(Cc), Bt2 = bc2(Bt);
        const float R2cut = EXPCUT / (-s_nisr2);   // uniform (sigma uniform)
        int sprev = 0;
#define CLSF(C) { \
        const int send = __builtin_amdgcn_readfirstlane(ps[(C) + 1]); \
        for (int v = sprev; v < send; v += 2) { \
            const v2f rho2 = *reinterpret_cast<const v2f*>(&pv_rho[v]); \
            const float dA = rho2.x - mr, dB = rho2.y - mr; \
            const int okA = __any(dA * dA <= R2cut); \
            const int okB = __any(dB * dB <= R2cut); \
            if (okA | okB) { \
                const v2f a02 = *reinterpret_cast<const v2f*>(&pv_a0[v]); \
                const v2f va2 = *reinterpret_cast<const v2f*>(&pv_va[v]); \
                const v2f bv2 = *reinterpret_cast<const v2f*>(&pv_bv[v]); \
                const v2f s2  = *reinterpret_cast<const v2f*>(&pv_x[fb][v]); \
                const v2f tt = pk_fma(a02, ct1_2, pk_fma(rho2, ct2_2, pk_add(va2, Cc2))); \
                const v2f Bab = pk_mul(bv2, Bt2); \
                const float MsA = fexp2(tt.x) * s2.x; \
                const float MsB = fexp2(tt.y) * s2.y; \
                if (okA) chain<(C)>(Kp, aggE, aggO, MsA, Bab.x); \
                if (okB) chain<(C)>(Kp, aggE, aggO, MsB, Bab.y); \
            } \
        } \
        sprev = send; }
        CLSF(0)  CLSF(1)  CLSF(2)  CLSF(3)
        CLSF(4)  CLSF(5)  CLSF(6)  CLSF(7)
        CLSF(8)  CLSF(9)  CLSF(10) CLSF(11)
        CLSF(12) CLSF(13) CLSF(14) CLSF(15)
#undef CLSF
    } else {
        // exact fallback: per-thread sigma, 2 exp2/vertex, no cull
        int sprev = 0;
#define CLSS(C) { \
        const int send = __builtin_amdgcn_readfirstlane(ps[(C) + 1]); \
        for (int v = sprev; v < send; v += 2) { \
            const v2f rho2 = *reinterpret_cast<const v2f*>(&pv_rho[v]); \
            const v2f a02  = *reinterpret_cast<const v2f*>(&pv_a0[v]); \
            const v2f s2   = *reinterpret_cast<const v2f*>(&pv_x[fb][v]); \
            const float drA = rho2.x - mr, xA = a02.x - mt; \
            const float arA = (drA * drA) * nisr2; \
            const float MA = fexp2(fmaf(xA * xA, nist2, arA)) * s2.x; \
            const float BA = fexp2(xA * c1); \
            const float drB = rho2.y - mr, xB = a02.y - mt; \
            const float arB = (drB * drB) * nisr2; \
            const float MB = fexp2(fmaf(xB * xB, nist2, arB)) * s2.y; \
            const float BBv = fexp2(xB * c1); \
            chain<(C)>(Kp, aggE, aggO, MA, BA); \
            chain<(C)>(Kp, aggE, aggO, MB, BBv); \
        } \
        sprev = send; }
        CLSS(0)  CLSS(1)  CLSS(2)  CLSS(3)
        CLSS(4)  CLSS(5)  CLSS(6)  CLSS(7)
        CLSS(8)  CLSS(9)  CLSS(10) CLSS(11)
        CLSS(12) CLSS(13) CLSS(14) CLSS(15)
#undef CLSS
    }
    __syncthreads();   // B3.5: all pv/ps reads done -> aggL may overlay

    // combine dual accumulators -> r-space, write to LDS (band mapping!)
    #pragma unroll
    for (int k = 0; k < 8; ++k) {
        aggL[fb][2 * k][gb]     = aggE[k].x + aggO[(k + 7) & 7].y;
        aggL[fb][2 * k + 1][gb] = aggE[k].y + aggO[k].x;
    }
    __syncthreads();   // B4: aggL ready

    // ---- conv GEMV (pk) + relu + max over rotations (flat mapping) ----
    v2f racc2[RR];
    {
        const float cb = conv_b[f * GG + g];
        #pragma unroll
        for (int r = 0; r < RR; ++r) { racc2[r].x = cb; racc2[r].y = 0.f; }
    }
    for (int g4 = 0; g4 < GG; g4 += 4) {
        const float* wp = &conv_W[(f * GG + g4) * GG + g];
        v2f wA, wB;
        wA.x = wp[0];      wA.y = wp[GG];
        wB.x = wp[2 * GG]; wB.y = wp[3 * GG];
        #pragma unroll
        for (int r = 0; r < RR; ++r) {
            const float4 a4 = *reinterpret_cast<const float4*>(&aggL[f][r][g4]);
            v2f aA, aB;
            aA.x = a4.x; aA.y = a4.y;
            aB.x = a4.z; aB.y = a4.w;
            racc2[r] = pk_fma(aA, wA, racc2[r]);
            racc2[r] = pk_fma(aB, wB, racc2[r]);
        }
    }
    float mxr = racc2[0].x + racc2[0].y;
    #pragma unroll
    for (int r = 1; r < RR; ++r) mxr = fmaxf(mxr, racc2[r].x + racc2[r].y);
    desc_s[f * GG + g] = fmaxf(mxr, 0.0f);   // disjoint from aggL region

    __syncthreads();   // B5: desc ready

    // ---- fc1 + relu (pk, 4-way k-split over f) ----
    {
        const v2f* wrow = reinterpret_cast<const v2f*>(&fc1_W[g * (FF * GG) + f * GG]);
        const v2f* drow = reinterpret_cast<const v2f*>(&desc_s[f * GG]);
        v2f a2; a2.x = 0.f; a2.y = 0.f;
        #pragma unroll 4
        for (int k = 0; k < GG / 2; ++k) a2 = pk_fma(drow[k], wrow[k], a2);
        hp_s[f * GG + g] = a2.x + a2.y;
    }
    __syncthreads();   // B6: hp ready
    if (t < GG) {
        const float a1 = ((hp_s[t] + hp_s[GG + t]) + (hp_s[2 * GG + t] + hp_s[3 * GG + t]))
                         + fc1_b[t];
        xbuf[b * GG + t] = fmaxf(a1, 0.0f);
    }
}

// ---------------------------------------------------------------------------
// Kernel B: partial gram. 64 blocks x 64 samples; deterministic.
// ---------------------------------------------------------------------------
__global__ __launch_bounds__(256) void gram_partial(
    const float* __restrict__ xbuf,   // [B,G]
    float* __restrict__ gpart)        // [64, G*G]
{
    const int blk = blockIdx.x;
    const int t = threadIdx.x;
    __shared__ float xs[64][GG];

    for (int i = t; i < 64 * GG; i += 256) {
        int bb = i / GG, jj = i % GG;
        xs[bb][jj] = xbuf[(blk * 64 + bb) * GG + jj];
    }
    __syncthreads();

    const int ti = t / 16, tj = t % 16;
    float acc[5][5];
    #pragma unroll
    for (int u = 0; u < 5; ++u)
        #pragma unroll
        for (int w = 0; w < 5; ++w) acc[u][w] = 0.0f;

    for (int bb = 0; bb < 64; ++bb) {
        float xi[5], xj[5];
        #pragma unroll
        for (int u = 0; u < 5; ++u) { xi[u] = xs[bb][ti * 5 + u]; xj[u] = xs[bb][tj * 5 + u]; }
        #pragma unroll
        for (int u = 0; u < 5; ++u)
            #pragma unroll
            for (int w = 0; w < 5; ++w)
                acc[u][w] = fmaf(xi[u], xj[w], acc[u][w]);
    }

    #pragma unroll
    for (int u = 0; u < 5; ++u)
        #pragma unroll
        for (int w = 0; w < 5; ++w)
            gpart[blk * (GG * GG) + (ti * 5 + u) * GG + (tj * 5 + w)] = acc[u][w];
}

// ---------------------------------------------------------------------------
// Kernel C1: 64 blocks; block p owns k-range [p*100, p*100+100): reduce gram
// partials (ordered, deterministic) and compute partial fc2 dot products.
// ---------------------------------------------------------------------------
__global__ __launch_bounds__(128) void head_partial(
    const float* __restrict__ gpart,  // [64, G*G]
    const float* __restrict__ fc2_W,  // [64, G*G]
    float* __restrict__ hpp)          // [64, 64]
{
    const int p = blockIdx.x;   // 0..63
    const int t = threadIdx.x;
    __shared__ float gs[100];

    if (t < 100) {
        const int k = p * 100 + t;
        float s = 0.f;
        #pragma unroll 8
        for (int q = 0; q < 64; ++q) s += gpart[q * (GG * GG) + k];
        gs[t] = s * (1.0f / 4096.0f);
    }
    __syncthreads();
    if (t < 64) {
        const float* w = &fc2_W[t * (GG * GG) + p * 100];
        float a = 0.f;
        #pragma unroll 4
        for (int k = 0; k < 100; ++k) a = fmaf(gs[k], w[k], a);
        hpp[p * 64 + t] = a;
    }
}

// ---------------------------------------------------------------------------
// Kernel C2: reduce hpp (ordered), fc2 bias+relu, fco head.
// ---------------------------------------------------------------------------
__global__ __launch_bounds__(256) void head_final(
    const float* __restrict__ hpp,    // [64, 64]
    const float* __restrict__ fc2_b,  // [64]
    const float* __restrict__ fco_W,  // [NLIG, 64]
    const float* __restrict__ fco_b,  // [NLIG]
    float* __restrict__ out)          // [NLIG]
{
    const int t = threadIdx.x;
    const int part = t >> 6, j = t & 63;
    __shared__ float hq[4][64];
    __shared__ float hs[64];
    float a = 0.f;
    #pragma unroll 4
    for (int p = part * 16; p < part * 16 + 16; ++p) a += hpp[p * 64 + j];
    hq[part][j] = a;
    __syncthreads();
    if (t < 64)
        hs[t] = fmaxf(((hq[0][t] + hq[1][t]) + (hq[2][t] + hq[3][t])) + fc2_b[t], 0.0f);
    __syncthreads();
    if (t < NLIG) {
        float o = fco_b[t];
        #pragma unroll
        for (int jj = 0; jj < 64; ++jj) o = fmaf(hs[jj], fco_W[t * 64 + jj], o);
        out[t] = o;
    }
}

// ---------------------------------------------------------------------------
extern "C" void kernel_launch(void* const* d_in, const int* in_sizes, int n_in,
                              void* d_out, int out_size, void* d_ws, size_t ws_size,
                              hipStream_t stream) {
    const float* input_feat  = (const float*)d_in[0];
    const float* rho         = (const float*)d_in[1];
    const float* theta       = (const float*)d_in[2];
    const float* mask        = (const float*)d_in[3];
    const float* mu_rho      = (const float*)d_in[4];
    const float* mu_theta    = (const float*)d_in[5];
    const float* sigma_rho   = (const float*)d_in[6];
    const float* sigma_theta = (const float*)d_in[7];
    const float* conv_W      = (const float*)d_in[8];
    const float* conv_b      = (const float*)d_in[9];
    const float* fc1_W       = (const float*)d_in[10];
    const float* fc1_b       = (const float*)d_in[11];
    const float* fc2_W       = (const float*)d_in[12];
    const float* fc2_b       = (const float*)d_in[13];
    const float* fco_W       = (const float*)d_in[14];
    const float* fco_b       = (const float*)d_in[15];

    float* xbuf  = (float*)d_ws;                                      // [B,G]
    float* gpart = (float*)((char*)d_ws + (size_t)BB * GG * 4);       // [64,6400]
    float* hpp   = (float*)((char*)d_ws + (size_t)BB * GG * 4
                                        + (size_t)64 * GG * GG * 4);  // [64,64]

    masif_main<<<BB, 320, 0, stream>>>(input_feat, rho, theta, mask,
                                       mu_rho, mu_theta, sigma_rho, sigma_theta,
                                       conv_W, conv_b, fc1_W, fc1_b, xbuf);
    gram_partial<<<64, 256, 0, stream>>>(xbuf, gpart);
    head_partial<<<64, 128, 0, stream>>>(gpart, fc2_W, hpp);
    head_final<<<1, 256, 0, stream>>>(hpp, fc2_b, fco_W, fco_b, (float*)d_out);
}